// Round 14
// baseline (476.561 us; speedup 1.0000x reference)
//
#include <hip/hip_runtime.h>
#include <hip/hip_bf16.h>
#include <cstdint>
#include <cstddef>

#define KS 5
#define K3 125

typedef __attribute__((ext_vector_type(8))) short bf16x8;
typedef __attribute__((ext_vector_type(4))) float f32x4;

struct PreArgs {
    const int* src[5]; const int* dst[5];
    int* cnt[5]; int* slots[5];
    int E[5];
    const float* W[5]; unsigned short* Wt[5];
    int Kd[5], KdP[5], Co[5];
    int fillFirst[6]; int wtFirst[6]; int ktiles[5];
    int cpg[5];   // fill chunks per graph (0 => linear mapping)
};

__device__ __forceinline__ unsigned f2ord(float f){
    unsigned u = __float_as_uint(f);
    return (u & 0x80000000u) ? ~u : (u | 0x80000000u);
}
__device__ __forceinline__ float ord2f(unsigned u){
    unsigned b = (u & 0x80000000u) ? (u & 0x7FFFFFFFu) : ~u;
    return __uint_as_float(b);
}
__device__ __forceinline__ unsigned short f2bf(float f){
    unsigned u = __float_as_uint(f);
    u = (u + 0x7FFFu + ((u >> 16) & 1u)) >> 16;
    return (unsigned short)u;
}
__device__ __forceinline__ unsigned pk_bf16(float a, float b){
    __hip_bfloat162 p = __float22bfloat162_rn(make_float2(a, b));
    return *(unsigned*)&p;
}

// ---------------- fused preamble: capacity-slot fill (XCD-swizzled) + W transpose ----------------
__global__ __launch_bounds__(256) void k_pre2(PreArgs a){
    __shared__ float t[64][65];
    int b = blockIdx.x;
    int tid = threadIdx.x;
    if(b < a.fillFirst[5]){
        int l = 0;
        while(b >= a.fillFirst[l+1]) l++;
        int j = b - a.fillFirst[l];
        int C = a.cpg[l];
        int e;
        if(C > 0){
            // all chunks of graph g get block ids == g (mod 8) -> same XCD L2
            int group = j / (8*C);
            int r = j - group*8*C;
            int c = r >> 3;
            int gx = r & 7;
            int g = group*8 + gx;
            e = (g*C + c)*256 + tid;
        } else {
            e = j*256 + tid;
        }
        if(e < a.E[l]){
            int d = a.dst[l][e];
            int s = a.src[l][e];
            int p = atomicAdd(&a.cnt[l][d], 1);
            if(p < 64) a.slots[l][(size_t)d*64 + p] = s;
        }
        return;
    }
    int r = b - a.fillFirst[5];
    int l = 0;
    while(r >= a.wtFirst[l+1]) l++;
    int idx = r - a.wtFirst[l];
    int kb = (idx % a.ktiles[l])*64;
    int cb = (idx / a.ktiles[l])*64;
    int Kd = a.Kd[l], KdP = a.KdP[l], Co = a.Co[l];
    const float* W = a.W[l];
    unsigned short* Wt = a.Wt[l];
    int cc = tid & 63, rg = tid >> 6;
    #pragma unroll
    for(int i=0;i<16;i++){
        int kl = rg + i*4;
        int kk = kb + kl, co = cb + cc;
        t[kl][cc] = (kk < Kd && co < Co) ? W[(size_t)kk*Co + co] : 0.f;
    }
    __syncthreads();
    int kl = tid & 63;
    #pragma unroll
    for(int i=0;i<16;i++){
        int col = rg + i*4;
        int co = cb + col;
        int kk = kb + kl;
        if(co < Co && kk < KdP) Wt[(size_t)co*KdP + kk] = f2bf(t[kl][col]);
    }
}

// ---------------- spline basis helper ----------------
__device__ __forceinline__ void spline_meta(float dx, float dy, float dz, float inv2r,
        float* wgt, int* ki){
    float fr[3]; int k0[3];
    float dd[3] = {dx, dy, dz};
    #pragma unroll
    for(int dim=0; dim<3; dim++){
        float p = dd[dim]*inv2r + 0.5f;
        p = fminf(fmaxf(p, 0.f), 1.f);
        float u = p*4.0f;
        float kf = fminf(floorf(u), 3.f);
        fr[dim] = u - kf; k0[dim] = (int)kf;
    }
    #pragma unroll
    for(int bits=0; bits<8; bits++){
        wgt[bits] = ((bits&1)? fr[0] : 1.f-fr[0])
                  * ((bits&2)? fr[1] : 1.f-fr[1])
                  * ((bits&4)? fr[2] : 1.f-fr[2]);
        ki[bits]  = (k0[0]+(bits&1)) + KS*(k0[1]+((bits>>1)&1)) + KS*KS*(k0[2]+((bits>>2)&1));
    }
}

// ---------------- build A, 32-ci-slice per block, 16-group float2 drain ----------------
__global__ __launch_bounds__(256) void k_build2(const int* __restrict__ slots,
        const int* __restrict__ cnt, const float* __restrict__ pos,
        const float* __restrict__ x,
        float inv2r, int n0, int Cin, int KdP, unsigned short* __restrict__ A){
    const int CH = 32;
    __shared__ float row[K3*32];
    __shared__ float xbuf[CH*32];
    __shared__ float ew[CH][8];
    __shared__ unsigned short bkt[16][CH];
    __shared__ int bcnt[16];
    __shared__ int esrc[CH];
    int tid = threadIdx.x;
    int node = n0 + blockIdx.x;
    int ci0 = blockIdx.y*32;
    for(int i=tid; i<K3*32; i+=256) row[i] = 0.f;
    int ecnt = min(cnt[node], 64);
    const int* sl = slots + (size_t)node*64;
    float pdx = pos[node*3+0], pdy = pos[node*3+1], pdz = pos[node*3+2];

    for(int c0=0; c0<ecnt; c0+=CH){
        int cc2 = min(CH, ecnt-c0);
        __syncthreads();
        if(tid < 16) bcnt[tid] = 0;
        float w[8]; int ki[8];
        if(tid < cc2){
            int s = sl[c0+tid];
            esrc[tid] = s;
            spline_meta(pdx-pos[s*3+0], pdy-pos[s*3+1], pdz-pos[s*3+2], inv2r, w, ki);
            #pragma unroll
            for(int b=0;b<8;b++) ew[tid][b] = w[b];
        }
        __syncthreads();
        if(tid < cc2){
            #pragma unroll
            for(int b=0;b<8;b++){
                int g = ki[b] & 15;
                int p = atomicAdd(&bcnt[g], 1);
                bkt[g][p] = (unsigned short)((ki[b]<<8) | (tid<<3) | b);
            }
        }
        for(int i=tid; i<cc2*32; i+=256){
            int e = i >> 5, ci = i & 31;
            xbuf[i] = x[(size_t)esrc[e]*Cin + ci0 + ci];
        }
        __syncthreads();
        int g  = tid >> 4;
        int cl = (tid & 15)*2;
        int ng = bcnt[g];
        for(int i=0; i<ng; i++){
            unsigned v = bkt[g][i];
            int kq = v >> 8;
            int e  = (v >> 3) & 31;
            float wv = ew[e][v & 7];
            float2 xv = *(float2*)&xbuf[e*32 + cl];
            float2* rp = (float2*)&row[kq*32 + cl];
            float2 rv = *rp;
            rv.x += wv*xv.x;
            rv.y += wv*xv.y;
            *rp = rv;
        }
    }
    __syncthreads();
    size_t gbase = (size_t)blockIdx.x*KdP + ci0;
    for(int i=tid*4; i<K3*32; i+=1024){
        int k = i >> 5, c = i & 31;
        uint2 pk;
        pk.x = pk_bf16(row[i],   row[i+1]);
        pk.y = pk_bf16(row[i+2], row[i+3]);
        *(uint2*)&A[gbase + (size_t)k*Cin + c] = pk;
    }
}

// ---------------- build for Cin==1 (layer 1) ----------------
__global__ __launch_bounds__(256) void k_build1(const int* __restrict__ slots,
        const int* __restrict__ cnt, const float* __restrict__ pos,
        const float* __restrict__ x,
        float inv2r, int n0, int KdP, unsigned short* __restrict__ A){
    const int NB = 32, KD = K3;
    __shared__ float rows[NB*KD];
    int tid = threadIdx.x;
    for(int i=tid; i<NB*KD; i+=256) rows[i] = 0.f;
    __syncthreads();
    int nb = tid >> 3;
    int grp = tid & 7;
    int node = n0 + blockIdx.x*NB + nb;
    float* row = rows + nb*KD;
    float pdx = pos[node*3+0], pdy = pos[node*3+1], pdz = pos[node*3+2];
    int ecnt = min(cnt[node], 64);
    const int* sl = slots + (size_t)node*64;
    for(int ii=grp; ii<ecnt; ii+=8){
        int s = sl[ii];
        float w[8]; int ki[8];
        spline_meta(pdx-pos[s*3+0], pdy-pos[s*3+1], pdz-pos[s*3+2], inv2r, w, ki);
        float xs = x[s];
        #pragma unroll
        for(int b=0; b<8; b++)
            __hip_atomic_fetch_add(&row[ki[b]], w[b]*xs, __ATOMIC_RELAXED, __HIP_MEMORY_SCOPE_WORKGROUP);
    }
    __syncthreads();
    size_t gbase = (size_t)blockIdx.x*NB*KdP;
    int tot = NB*KdP;
    for(int i=tid*2; i<tot; i+=512){
        int nbw = i / KdP;
        int kk  = i - nbw*KdP;
        float v0 = (kk   < KD) ? rows[nbw*KD + kk]   : 0.f;
        float v1 = (kk+1 < KD) ? rows[nbw*KD + kk+1] : 0.f;
        *(unsigned*)&A[gbase + i] = pk_bf16(v0, v1);
    }
}

// ---------------- MFMA GEMM (BN in {32,64}) ----------------
template<int BN>
__global__ __launch_bounds__(256) void k_mfma(const unsigned short* __restrict__ A,
        const unsigned short* __restrict__ Wt, float* __restrict__ acc,
        int n0, int Co, int KdP, int Kper){
    const int NBF = BN/16;
    __shared__ unsigned short Al[128*32];
    __shared__ unsigned short Bl[BN*32];
    int tid = threadIdx.x;
    int m0 = blockIdx.x*128, nb0 = blockIdx.y*BN;
    int kstart = blockIdx.z*Kper;
    int kend = min(KdP, kstart + Kper);
    if(kstart >= kend) return;
    int w = tid >> 6, l = tid & 63, lm = l & 15, lk = l >> 4;
    f32x4 c[2][NBF];
    #pragma unroll
    for(int i=0;i<2;i++)
        #pragma unroll
        for(int j=0;j<NBF;j++) c[i][j] = (f32x4){0,0,0,0};
    int ar = tid >> 1, ah = (tid & 1)*16;

    for(int k0=kstart; k0<kend; k0+=32){
        const unsigned short* ga = A + (size_t)(m0+ar)*KdP + k0 + ah;
        *(uint4*)&Al[ar*32 + ah]     = *(const uint4*)ga;
        *(uint4*)&Al[ar*32 + ah + 8] = *(const uint4*)(ga + 8);
        if(tid < BN*4){
            int bn = tid >> 2, bk = (tid & 3)*8;
            *(uint4*)&Bl[bn*32 + bk] = *(const uint4*)(Wt + (size_t)(nb0+bn)*KdP + k0 + bk);
        }
        __syncthreads();
        bf16x8 af[2], bfr[NBF];
        #pragma unroll
        for(int i=0;i<2;i++) af[i] = *(bf16x8*)&Al[(w*32 + i*16 + lm)*32 + lk*8];
        #pragma unroll
        for(int j=0;j<NBF;j++) bfr[j] = *(bf16x8*)&Bl[(j*16 + lm)*32 + lk*8];
        #pragma unroll
        for(int i=0;i<2;i++)
            #pragma unroll
            for(int j=0;j<NBF;j++)
                c[i][j] = __builtin_amdgcn_mfma_f32_16x16x32_bf16(af[i], bfr[j], c[i][j], 0,0,0);
        __syncthreads();
    }
    #pragma unroll
    for(int i=0;i<2;i++){
        int mb = n0 + m0 + w*32 + i*16 + lk*4;
        #pragma unroll
        for(int j=0;j<NBF;j++){
            int col = nb0 + j*16 + lm;
            if(gridDim.z == 1){
                #pragma unroll
                for(int r=0;r<4;r++) acc[(size_t)(mb+r)*Co + col] = c[i][j][r];
            } else {
                #pragma unroll
                for(int r=0;r<4;r++) atomicAdd(&acc[(size_t)(mb+r)*Co + col], c[i][j][r]);
            }
        }
    }
}

// ---------------- conv epilogue + fused attention-pool atomics ----------------
__global__ void k_finish2(const float* __restrict__ acc, const int* __restrict__ deg,
        const float* __restrict__ xin, const float* __restrict__ root,
        const float* __restrict__ bias, const float* __restrict__ Wa,
        const float* __restrict__ ba, float* __restrict__ y,
        const int* __restrict__ cl, const float* __restrict__ pin,
        unsigned long long* __restrict__ m_p, float* __restrict__ cntf,
        float* __restrict__ ppos, int N, int Cin, int Co, int NPB){
    extern __shared__ float sm[];
    float* xs  = sm;
    float* red = sm + NPB*Cin;
    int tid = threadIdx.x;
    int nl = tid / Co, co = tid - nl*Co;
    int n = blockIdx.x*NPB + nl;
    bool act = (n < N);
    if(act) for(int c=co; c<Cin; c+=Co) xs[nl*Cin + c] = xin[(size_t)n*Cin + c];
    __syncthreads();
    float yv = 0.f;
    if(act){
        float v = acc[(size_t)n*Co + co] / (float)max(deg[n], 1);
        float rt = 0.f;
        for(int c=0; c<Cin; c++) rt += xs[nl*Cin + c]*root[(size_t)c*Co + co];
        v += rt + bias[co];
        yv = v > 0.f ? v : expm1f(v);
        y[(size_t)n*Co + co] = yv;
    }
    if(m_p){
        float av = act ? yv * Wa[co*2] : 0.f;
        if(Co <= 64){
            #pragma unroll
            for(int off=32; off>0; off>>=1)
                if(off < Co) av += __shfl_xor(av, off, 64);
        } else {
            red[tid] = av;
            __syncthreads();
            int cur = Co;
            while(cur > 1){
                int half = (cur+1) >> 1;
                if(co < cur-half) red[nl*Co+co] += red[nl*Co+co+half];
                __syncthreads();
                cur = half;
            }
            av = red[nl*Co];
        }
        if(act && co==0){
            float attv = av + ba[0];
            int c = cl[n];
            unsigned long long pk = ((unsigned long long)f2ord(attv) << 32) | (unsigned)(~n);
            atomicMax(&m_p[c], pk);
            atomicAdd(&cntf[c], 1.f);
            atomicAdd(&ppos[c*3+0], pin[n*3+0]);
            atomicAdd(&ppos[c*3+1], pin[n*3+1]);
            atomicAdd(&ppos[c*3+2], pin[n*3+2]);
        }
    }
}

// ---------------- pool gather ----------------
__global__ void k_pool3(const unsigned long long* __restrict__ m_p, const float* __restrict__ cntf,
        const float* __restrict__ ppos, const float* __restrict__ x,
        float* __restrict__ xo, float* __restrict__ poso, int nc, int Co, int nmax){
    int t = blockIdx.x*blockDim.x + threadIdx.x;
    if(t >= nc*Co) return;
    int c = t / Co;
    int co = t - c*Co;
    unsigned s = ~(unsigned)(m_p[c] & 0xFFFFFFFFull);
    s = min(s, (unsigned)(nmax-1));
    xo[(size_t)c*Co + co] = x[(size_t)s*Co + co];
    if(co < 3) poso[c*3+co] = ppos[c*3+co] / fmaxf(cntf[c], 1.f);
}

// ---------------- final voxel max pool ----------------
__global__ void k_vox(const float* __restrict__ x, const float* __restrict__ pos,
        unsigned* __restrict__ mx_u, float* __restrict__ cnt8){
    int nidx = blockIdx.x, ch = threadIdx.x;
    int v0 = min(max((int)floorf(pos[nidx*3+0]+0.5f),0),1);
    int v1 = min(max((int)floorf(pos[nidx*3+1]+0.5f),0),1);
    int v2 = min(max((int)floorf(pos[nidx*3+2]+0.5f),0),1);
    int b = nidx >> 3;
    int cl = b*8 + v0*4 + v1*2 + v2;
    atomicMax(&mx_u[cl*256+ch], f2ord(x[nidx*256+ch]));
    if(ch==0) atomicAdd(&cnt8[cl], 1.f);
}

// ---------------- FC + log_softmax ----------------
__global__ __launch_bounds__(256) void k_fc(const unsigned* __restrict__ mx_u,
        const float* __restrict__ cnt8, const float* __restrict__ Wfc,
        const float* __restrict__ bfc, float* __restrict__ out){
    __shared__ float sred[10][256];
    int b = blockIdx.x, tid = threadIdx.x;
    float p[10];
    #pragma unroll
    for(int j=0;j<10;j++) p[j]=0.f;
    for(int idx=tid; idx<2048; idx+=256){
        int v = idx >> 8;
        float val = (cnt8[b*8+v] > 0.f) ? ord2f(mx_u[b*2048+idx]) : 0.f;
        const float* wr = &Wfc[idx*10];
        #pragma unroll
        for(int j=0;j<10;j++) p[j] += val*wr[j];
    }
    #pragma unroll
    for(int j=0;j<10;j++) sred[j][tid]=p[j];
    __syncthreads();
    for(int s=128;s>0;s>>=1){
        if(tid<s){
            #pragma unroll
            for(int j=0;j<10;j++) sred[j][tid]+=sred[j][tid+s];
        }
        __syncthreads();
    }
    if(tid==0){
        float lg[10], mx=-1e30f, se=0.f;
        for(int j=0;j<10;j++){ lg[j]=sred[j][0]+bfc[j]; mx=fmaxf(mx,lg[j]); }
        for(int j=0;j<10;j++) se += expf(lg[j]-mx);
        float lse = mx + logf(se);
        for(int j=0;j<10;j++) out[b*10+j] = lg[j]-lse;
    }
}

extern "C" void kernel_launch(void* const* d_in, const int* in_sizes, int n_in,
                              void* d_out, int out_size, void* d_ws, size_t ws_size,
                              hipStream_t stream){
    const float* x0   = (const float*)d_in[0];
    const float* pos0 = (const float*)d_in[1];
    const float *Wc[5], *rootc[5], *bc[5];
    for(int i=0;i<5;i++){
        Wc[i]    = (const float*)d_in[2+3*i];
        rootc[i] = (const float*)d_in[3+3*i];
        bc[i]    = (const float*)d_in[4+3*i];
    }
    const float *Wa[4], *ba[4];
    for(int i=0;i<4;i++){
        Wa[i] = (const float*)d_in[17+2*i];
        ba[i] = (const float*)d_in[18+2*i];
    }
    const float* Wfc = (const float*)d_in[25];
    const float* bfc = (const float*)d_in[26];
    const int* ei[5]; for(int i=0;i<5;i++) ei[i] = (const int*)d_in[27+i];
    const int* cl[4]; for(int i=0;i<4;i++) cl[i] = (const int*)d_in[32+i];

    const int NPG[5]   = {2048,512,128,32,8};
    const int chans[6] = {1,32,64,96,128,256};
    const float inv2r[5] = {5.f,5.f,4.f,2.f,1.f};
    const int B = 32;
    int Ns[5], Es[5], KdPs[5];
    int totN=0, totWt=0, accTotZ=0, poolTot=0;
    int nodeBase[5], wtBase[5], accOffZ[5], poolOff[4];
    for(int l=0;l<5;l++){
        Ns[l] = B*NPG[l]; Es[l] = Ns[l]*16;
        int Kd = K3*chans[l];
        KdPs[l] = (Kd + 31) & ~31;
        nodeBase[l] = totN; totN += Ns[l];
        wtBase[l] = totWt; totWt += chans[l+1]*KdPs[l];
        if(l >= 1){ accOffZ[l] = accTotZ; accTotZ += Ns[l]*chans[l+1]; }
    }
    for(int l=0;l<4;l++){ poolOff[l] = poolTot; poolTot += Ns[l+1]; }

    size_t off = 0;
    auto alloc = [&](size_t bytes)->void*{
        void* p = (char*)d_ws + off;
        off = (off + bytes + 255) & ~(size_t)255;
        return p;
    };
    // ---- non-zeroed region ----
    float*    x_a    = (float*)   alloc((size_t)65536*32*4);
    float*    x_b    = (float*)   alloc((size_t)16384*32*4);
    float*    pos_a  = (float*)   alloc((size_t)16384*3*4);
    float*    pos_b  = (float*)   alloc((size_t)4096*3*4);
    float*    acc0   = (float*)   alloc((size_t)65536*32*4);   // L1 acc (S==1, no zero)
    int*      slots_a= (int*)     alloc((size_t)totN*64*4);
    unsigned short* Wt_a = (unsigned short*)alloc((size_t)totWt*2);
    // ---- zero region (single memset) ----
    size_t zstart = off;
    int*      cnt_a  = (int*)     alloc((size_t)totN*4);
    float*    accz_a = (float*)   alloc((size_t)accTotZ*4);
    unsigned long long* m_p_a = (unsigned long long*)alloc((size_t)poolTot*8);
    float*    cntf_a = (float*)   alloc((size_t)poolTot*4);
    float*    ppos_a = (float*)   alloc((size_t)poolTot*12);
    unsigned* mx_u   = (unsigned*)alloc((size_t)256*256*4);
    float*    cnt8   = (float*)   alloc((size_t)256*4);
    size_t zlen = off - zstart;
    // ---- A tail ----
    unsigned short* A = (unsigned short*)((char*)d_ws + off);
    size_t Abudget = (ws_size > off) ? (ws_size - off) : 0;

    PreArgs pa;
    int fb = 0, wb = 0;
    for(int l=0;l<5;l++){
        pa.src[l] = ei[l];
        pa.dst[l] = ei[l] + Es[l];
        pa.cnt[l] = cnt_a + nodeBase[l];
        pa.slots[l] = slots_a + (size_t)nodeBase[l]*64;
        pa.E[l] = Es[l];
        pa.W[l] = Wc[l]; pa.Wt[l] = Wt_a + wtBase[l];
        pa.Kd[l] = K3*chans[l]; pa.KdP[l] = KdPs[l]; pa.Co[l] = chans[l+1];
        pa.fillFirst[l] = fb; fb += (Es[l] + 255)/256;
        int epg = NPG[l]*16;               // edges per graph (contiguous in edge list)
        pa.cpg[l] = (epg % 256 == 0) ? epg/256 : 0;
        pa.ktiles[l] = (KdPs[l] + 63)/64;
        pa.wtFirst[l] = wb; wb += pa.ktiles[l] * ((chans[l+1] + 63)/64);
    }
    pa.fillFirst[5] = fb;
    pa.wtFirst[5] = wb;
    int preBlocks = fb + wb;

    hipMemsetAsync((char*)d_ws + zstart, 0, zlen, stream);
    k_pre2<<<preBlocks, 256, 0, stream>>>(pa);

    const float* xin = x0;
    const float* pin = pos0;

    for(int L=0; L<5; L++){
        int N  = Ns[L];
        int Cin = chans[L], Co = chans[L+1];
        int KdP = KdPs[L];
        const int* cntL   = cnt_a + nodeBase[L];
        const int* slotsL = slots_a + (size_t)nodeBase[L]*64;
        const unsigned short* WtL = pa.Wt[L];
        float* accL = (L == 0) ? acc0 : (accz_a + accOffZ[L]);

        size_t nodeb = (size_t)KdP*2;
        int Mc = (int)(Abudget / nodeb);
        Mc = (Mc / 128) * 128;
        if(Mc < 128) Mc = 128;
        if(Mc > N) Mc = N;

        for(int rn0=0; rn0<N; rn0+=Mc){
            int rn1 = (rn0+Mc < N) ? rn0+Mc : N;
            int Mr  = rn1 - rn0;
            if(Cin==1)
                k_build1<<<Mr/32, 256, 0, stream>>>(slotsL, cntL, pin, xin, inv2r[L], rn0, KdP, A);
            else
                k_build2<<<dim3(Mr, Cin/32), 256, 0, stream>>>(slotsL, cntL, pin, xin,
                                                               inv2r[L], rn0, Cin, KdP, A);

            int BN = (Co % 64 == 0) ? 64 : 32;
            int gx = Mr/128, gy = Co/BN;
            int S = 768/(gx*gy);
            if(S < 1) S = 1;
            if(L == 0) S = 1;   // acc0 is not pre-zeroed; must use plain stores
            int maxS = KdP/32;
            if(S > maxS) S = maxS;
            int Kper = ((KdP + S - 1)/S + 31) & ~31;
            S = (KdP + Kper - 1)/Kper;
            dim3 g(gx, gy, S);
            if(BN == 64) k_mfma<64><<<g, 256, 0, stream>>>(A, WtL, accL, rn0, Co, KdP, Kper);
            else         k_mfma<32><<<g, 256, 0, stream>>>(A, WtL, accL, rn0, Co, KdP, Kper);
        }

        float* y = x_a;
        int NPB = 256/Co; if(NPB < 1) NPB = 1;
        int thr = NPB*Co;
        size_t smb = (size_t)(NPB*Cin + NPB*Co)*4;
        bool haspool = (L < 4);
        k_finish2<<<(N+NPB-1)/NPB, thr, smb, stream>>>(accL, cntL, xin, rootc[L], bc[L],
            haspool?Wa[L]:nullptr, haspool?ba[L]:nullptr, y,
            haspool?cl[L]:nullptr, pin,
            haspool?(m_p_a+poolOff[L]):nullptr,
            haspool?(cntf_a+poolOff[L]):nullptr,
            haspool?(ppos_a+(size_t)poolOff[L]*3):nullptr,
            N, Cin, Co, NPB);

        if(haspool){
            int nc = Ns[L+1];
            float* pout = (L%2==0) ? pos_a : pos_b;
            k_pool3<<<(nc*Co+255)/256, 256, 0, stream>>>(m_p_a+poolOff[L], cntf_a+poolOff[L],
                ppos_a+(size_t)poolOff[L]*3, y, x_b, pout, nc, Co, N);
            xin = x_b; pin = pout;
        }
    }

    k_vox<<<256, 256, 0, stream>>>(x_a, pin, mx_u, cnt8);
    k_fc<<<32, 256, 0, stream>>>(mx_u, cnt8, Wfc, bfc, (float*)d_out);
}

// Round 15
// 451.220 us; speedup vs baseline: 1.0562x; 1.0562x over previous
//
#include <hip/hip_runtime.h>
#include <hip/hip_bf16.h>
#include <cstdint>
#include <cstddef>

#define KS 5
#define K3 125

typedef __attribute__((ext_vector_type(8))) short bf16x8;
typedef __attribute__((ext_vector_type(4))) float f32x4;

struct PreArgs {
    const int* src[5]; const int* dst[5];
    int* cnt[5]; int* slots[5];
    int npg[5];
    const float* W[5]; unsigned short* Wt[5];
    int Kd[5], KdP[5], Co[5];
    int fillFirst[6]; int wtFirst[6]; int ktiles[5];
};

__device__ __forceinline__ unsigned f2ord(float f){
    unsigned u = __float_as_uint(f);
    return (u & 0x80000000u) ? ~u : (u | 0x80000000u);
}
__device__ __forceinline__ float ord2f(unsigned u){
    unsigned b = (u & 0x80000000u) ? (u & 0x7FFFFFFFu) : ~u;
    return __uint_as_float(b);
}
__device__ __forceinline__ unsigned short f2bf(float f){
    unsigned u = __float_as_uint(f);
    u = (u + 0x7FFFu + ((u >> 16) & 1u)) >> 16;
    return (unsigned short)u;
}
__device__ __forceinline__ unsigned pk_bf16(float a, float b){
    __hip_bfloat162 p = __float22bfloat162_rn(make_float2(a, b));
    return *(unsigned*)&p;
}

// ---------------- fused preamble: per-graph LDS counting-sort fill + W transpose ----------------
// fill blocks: one per (layer, graph); LDS cnt[npg], zero global atomics.
// wt blocks: 64x64 transpose tiles (1024-thread variant).
__global__ __launch_bounds__(1024) void k_pre3(PreArgs a){
    __shared__ float smf[64*65];       // union: fill uses as int cnt[<=2048]; wt uses as t[64][65]
    int b = blockIdx.x;
    int tid = threadIdx.x;
    if(b < a.fillFirst[5]){
        int l = 0;
        while(b >= a.fillFirst[l+1]) l++;
        int g = b - a.fillFirst[l];
        int npg = a.npg[l];
        int E1 = npg*16;
        int nbase = g*npg;
        int* cnt = (int*)smf;
        for(int i=tid; i<npg; i+=1024) cnt[i] = 0;
        __syncthreads();
        const int* srcp = a.src[l] + (size_t)g*E1;
        const int* dstp = a.dst[l] + (size_t)g*E1;
        int* slots = a.slots[l];
        for(int e=tid; e<E1; e+=1024){
            int d = dstp[e];
            int s = srcp[e];
            int p = __hip_atomic_fetch_add(&cnt[d - nbase], 1,
                        __ATOMIC_RELAXED, __HIP_MEMORY_SCOPE_WORKGROUP);
            if(p < 64) slots[(size_t)d*64 + p] = s;
        }
        __syncthreads();
        int* cg = a.cnt[l];
        for(int i=tid; i<npg; i+=1024) cg[nbase + i] = cnt[i];
        return;
    }
    int r = b - a.fillFirst[5];
    int l = 0;
    while(r >= a.wtFirst[l+1]) l++;
    int idx = r - a.wtFirst[l];
    int kb = (idx % a.ktiles[l])*64;
    int cb = (idx / a.ktiles[l])*64;
    int Kd = a.Kd[l], KdP = a.KdP[l], Co = a.Co[l];
    const float* W = a.W[l];
    unsigned short* Wt = a.Wt[l];
    float (*t)[65] = (float(*)[65])smf;
    int cc = tid & 63, rg = tid >> 6;           // rg in [0,16)
    #pragma unroll
    for(int i=0;i<4;i++){
        int kl = rg + i*16;
        int kk = kb + kl, co = cb + cc;
        t[kl][cc] = (kk < Kd && co < Co) ? W[(size_t)kk*Co + co] : 0.f;
    }
    __syncthreads();
    int kl = tid & 63;
    #pragma unroll
    for(int i=0;i<4;i++){
        int col = rg + i*16;
        int co = cb + col;
        int kk = kb + kl;
        if(co < Co && kk < KdP) Wt[(size_t)co*KdP + kk] = f2bf(t[kl][col]);
    }
}

// ---------------- spline basis helper ----------------
__device__ __forceinline__ void spline_meta(float dx, float dy, float dz, float inv2r,
        float* wgt, int* ki){
    float fr[3]; int k0[3];
    float dd[3] = {dx, dy, dz};
    #pragma unroll
    for(int dim=0; dim<3; dim++){
        float p = dd[dim]*inv2r + 0.5f;
        p = fminf(fmaxf(p, 0.f), 1.f);
        float u = p*4.0f;
        float kf = fminf(floorf(u), 3.f);
        fr[dim] = u - kf; k0[dim] = (int)kf;
    }
    #pragma unroll
    for(int bits=0; bits<8; bits++){
        wgt[bits] = ((bits&1)? fr[0] : 1.f-fr[0])
                  * ((bits&2)? fr[1] : 1.f-fr[1])
                  * ((bits&4)? fr[2] : 1.f-fr[2]);
        ki[bits]  = (k0[0]+(bits&1)) + KS*(k0[1]+((bits>>1)&1)) + KS*KS*(k0[2]+((bits>>2)&1));
    }
}

// ---------------- build A, 32-ci-slice per block, 16-group float2 drain ----------------
__global__ __launch_bounds__(256) void k_build2(const int* __restrict__ slots,
        const int* __restrict__ cnt, const float* __restrict__ pos,
        const float* __restrict__ x,
        float inv2r, int n0, int Cin, int KdP, unsigned short* __restrict__ A){
    const int CH = 32;
    __shared__ float row[K3*32];
    __shared__ float xbuf[CH*32];
    __shared__ float ew[CH][8];
    __shared__ unsigned short bkt[16][CH];
    __shared__ int bcnt[16];
    __shared__ int esrc[CH];
    int tid = threadIdx.x;
    int node = n0 + blockIdx.x;
    int ci0 = blockIdx.y*32;
    for(int i=tid; i<K3*32; i+=256) row[i] = 0.f;
    int ecnt = min(cnt[node], 64);
    const int* sl = slots + (size_t)node*64;
    float pdx = pos[node*3+0], pdy = pos[node*3+1], pdz = pos[node*3+2];

    for(int c0=0; c0<ecnt; c0+=CH){
        int cc2 = min(CH, ecnt-c0);
        __syncthreads();
        if(tid < 16) bcnt[tid] = 0;
        float w[8]; int ki[8];
        if(tid < cc2){
            int s = sl[c0+tid];
            esrc[tid] = s;
            spline_meta(pdx-pos[s*3+0], pdy-pos[s*3+1], pdz-pos[s*3+2], inv2r, w, ki);
            #pragma unroll
            for(int b=0;b<8;b++) ew[tid][b] = w[b];
        }
        __syncthreads();
        if(tid < cc2){
            #pragma unroll
            for(int b=0;b<8;b++){
                int g = ki[b] & 15;
                int p = atomicAdd(&bcnt[g], 1);
                bkt[g][p] = (unsigned short)((ki[b]<<8) | (tid<<3) | b);
            }
        }
        for(int i=tid; i<cc2*32; i+=256){
            int e = i >> 5, ci = i & 31;
            xbuf[i] = x[(size_t)esrc[e]*Cin + ci0 + ci];
        }
        __syncthreads();
        int g  = tid >> 4;
        int cl = (tid & 15)*2;
        int ng = bcnt[g];
        for(int i=0; i<ng; i++){
            unsigned v = bkt[g][i];
            int kq = v >> 8;
            int e  = (v >> 3) & 31;
            float wv = ew[e][v & 7];
            float2 xv = *(float2*)&xbuf[e*32 + cl];
            float2* rp = (float2*)&row[kq*32 + cl];
            float2 rv = *rp;
            rv.x += wv*xv.x;
            rv.y += wv*xv.y;
            *rp = rv;
        }
    }
    __syncthreads();
    size_t gbase = (size_t)blockIdx.x*KdP + ci0;
    for(int i=tid*4; i<K3*32; i+=1024){
        int k = i >> 5, c = i & 31;
        uint2 pk;
        pk.x = pk_bf16(row[i],   row[i+1]);
        pk.y = pk_bf16(row[i+2], row[i+3]);
        *(uint2*)&A[gbase + (size_t)k*Cin + c] = pk;
    }
}

// ---------------- build for Cin==1 (layer 1) ----------------
__global__ __launch_bounds__(256) void k_build1(const int* __restrict__ slots,
        const int* __restrict__ cnt, const float* __restrict__ pos,
        const float* __restrict__ x,
        float inv2r, int n0, int KdP, unsigned short* __restrict__ A){
    const int NB = 32, KD = K3;
    __shared__ float rows[NB*KD];
    int tid = threadIdx.x;
    for(int i=tid; i<NB*KD; i+=256) rows[i] = 0.f;
    __syncthreads();
    int nb = tid >> 3;
    int grp = tid & 7;
    int node = n0 + blockIdx.x*NB + nb;
    float* row = rows + nb*KD;
    float pdx = pos[node*3+0], pdy = pos[node*3+1], pdz = pos[node*3+2];
    int ecnt = min(cnt[node], 64);
    const int* sl = slots + (size_t)node*64;
    for(int ii=grp; ii<ecnt; ii+=8){
        int s = sl[ii];
        float w[8]; int ki[8];
        spline_meta(pdx-pos[s*3+0], pdy-pos[s*3+1], pdz-pos[s*3+2], inv2r, w, ki);
        float xs = x[s];
        #pragma unroll
        for(int b=0; b<8; b++)
            __hip_atomic_fetch_add(&row[ki[b]], w[b]*xs, __ATOMIC_RELAXED, __HIP_MEMORY_SCOPE_WORKGROUP);
    }
    __syncthreads();
    size_t gbase = (size_t)blockIdx.x*NB*KdP;
    int tot = NB*KdP;
    for(int i=tid*2; i<tot; i+=512){
        int nbw = i / KdP;
        int kk  = i - nbw*KdP;
        float v0 = (kk   < KD) ? rows[nbw*KD + kk]   : 0.f;
        float v1 = (kk+1 < KD) ? rows[nbw*KD + kk+1] : 0.f;
        *(unsigned*)&A[gbase + i] = pk_bf16(v0, v1);
    }
}

// ---------------- MFMA GEMM (BN in {32,64}) ----------------
template<int BN>
__global__ __launch_bounds__(256) void k_mfma(const unsigned short* __restrict__ A,
        const unsigned short* __restrict__ Wt, float* __restrict__ acc,
        int n0, int Co, int KdP, int Kper){
    const int NBF = BN/16;
    __shared__ unsigned short Al[128*32];
    __shared__ unsigned short Bl[BN*32];
    int tid = threadIdx.x;
    int m0 = blockIdx.x*128, nb0 = blockIdx.y*BN;
    int kstart = blockIdx.z*Kper;
    int kend = min(KdP, kstart + Kper);
    if(kstart >= kend) return;
    int w = tid >> 6, l = tid & 63, lm = l & 15, lk = l >> 4;
    f32x4 c[2][NBF];
    #pragma unroll
    for(int i=0;i<2;i++)
        #pragma unroll
        for(int j=0;j<NBF;j++) c[i][j] = (f32x4){0,0,0,0};
    int ar = tid >> 1, ah = (tid & 1)*16;

    for(int k0=kstart; k0<kend; k0+=32){
        const unsigned short* ga = A + (size_t)(m0+ar)*KdP + k0 + ah;
        *(uint4*)&Al[ar*32 + ah]     = *(const uint4*)ga;
        *(uint4*)&Al[ar*32 + ah + 8] = *(const uint4*)(ga + 8);
        if(tid < BN*4){
            int bn = tid >> 2, bk = (tid & 3)*8;
            *(uint4*)&Bl[bn*32 + bk] = *(const uint4*)(Wt + (size_t)(nb0+bn)*KdP + k0 + bk);
        }
        __syncthreads();
        bf16x8 af[2], bfr[NBF];
        #pragma unroll
        for(int i=0;i<2;i++) af[i] = *(bf16x8*)&Al[(w*32 + i*16 + lm)*32 + lk*8];
        #pragma unroll
        for(int j=0;j<NBF;j++) bfr[j] = *(bf16x8*)&Bl[(j*16 + lm)*32 + lk*8];
        #pragma unroll
        for(int i=0;i<2;i++)
            #pragma unroll
            for(int j=0;j<NBF;j++)
                c[i][j] = __builtin_amdgcn_mfma_f32_16x16x32_bf16(af[i], bfr[j], c[i][j], 0,0,0);
        __syncthreads();
    }
    #pragma unroll
    for(int i=0;i<2;i++){
        int mb = n0 + m0 + w*32 + i*16 + lk*4;
        #pragma unroll
        for(int j=0;j<NBF;j++){
            int col = nb0 + j*16 + lm;
            if(gridDim.z == 1){
                #pragma unroll
                for(int r=0;r<4;r++) acc[(size_t)(mb+r)*Co + col] = c[i][j][r];
            } else {
                #pragma unroll
                for(int r=0;r<4;r++) atomicAdd(&acc[(size_t)(mb+r)*Co + col], c[i][j][r]);
            }
        }
    }
}

// ---------------- conv epilogue + fused attention-pool atomics ----------------
__global__ void k_finish2(const float* __restrict__ acc, const int* __restrict__ deg,
        const float* __restrict__ xin, const float* __restrict__ root,
        const float* __restrict__ bias, const float* __restrict__ Wa,
        const float* __restrict__ ba, float* __restrict__ y,
        const int* __restrict__ cl, const float* __restrict__ pin,
        unsigned long long* __restrict__ m_p, float* __restrict__ cntf,
        float* __restrict__ ppos, int N, int Cin, int Co, int NPB){
    extern __shared__ float sm[];
    float* xs  = sm;
    float* red = sm + NPB*Cin;
    int tid = threadIdx.x;
    int nl = tid / Co, co = tid - nl*Co;
    int n = blockIdx.x*NPB + nl;
    bool act = (n < N);
    if(act) for(int c=co; c<Cin; c+=Co) xs[nl*Cin + c] = xin[(size_t)n*Cin + c];
    __syncthreads();
    float yv = 0.f;
    if(act){
        float v = acc[(size_t)n*Co + co] / (float)max(deg[n], 1);
        float rt = 0.f;
        for(int c=0; c<Cin; c++) rt += xs[nl*Cin + c]*root[(size_t)c*Co + co];
        v += rt + bias[co];
        yv = v > 0.f ? v : expm1f(v);
        y[(size_t)n*Co + co] = yv;
    }
    if(m_p){
        float av = act ? yv * Wa[co*2] : 0.f;
        if(Co <= 64){
            #pragma unroll
            for(int off=32; off>0; off>>=1)
                if(off < Co) av += __shfl_xor(av, off, 64);
        } else {
            red[tid] = av;
            __syncthreads();
            int cur = Co;
            while(cur > 1){
                int half = (cur+1) >> 1;
                if(co < cur-half) red[nl*Co+co] += red[nl*Co+co+half];
                __syncthreads();
                cur = half;
            }
            av = red[nl*Co];
        }
        if(act && co==0){
            float attv = av + ba[0];
            int c = cl[n];
            unsigned long long pk = ((unsigned long long)f2ord(attv) << 32) | (unsigned)(~n);
            atomicMax(&m_p[c], pk);
            atomicAdd(&cntf[c], 1.f);
            atomicAdd(&ppos[c*3+0], pin[n*3+0]);
            atomicAdd(&ppos[c*3+1], pin[n*3+1]);
            atomicAdd(&ppos[c*3+2], pin[n*3+2]);
        }
    }
}

// ---------------- pool gather ----------------
__global__ void k_pool3(const unsigned long long* __restrict__ m_p, const float* __restrict__ cntf,
        const float* __restrict__ ppos, const float* __restrict__ x,
        float* __restrict__ xo, float* __restrict__ poso, int nc, int Co, int nmax){
    int t = blockIdx.x*blockDim.x + threadIdx.x;
    if(t >= nc*Co) return;
    int c = t / Co;
    int co = t - c*Co;
    unsigned s = ~(unsigned)(m_p[c] & 0xFFFFFFFFull);
    s = min(s, (unsigned)(nmax-1));
    xo[(size_t)c*Co + co] = x[(size_t)s*Co + co];
    if(co < 3) poso[c*3+co] = ppos[c*3+co] / fmaxf(cntf[c], 1.f);
}

// ---------------- final voxel max pool ----------------
__global__ void k_vox(const float* __restrict__ x, const float* __restrict__ pos,
        unsigned* __restrict__ mx_u, float* __restrict__ cnt8){
    int nidx = blockIdx.x, ch = threadIdx.x;
    int v0 = min(max((int)floorf(pos[nidx*3+0]+0.5f),0),1);
    int v1 = min(max((int)floorf(pos[nidx*3+1]+0.5f),0),1);
    int v2 = min(max((int)floorf(pos[nidx*3+2]+0.5f),0),1);
    int b = nidx >> 3;
    int cl = b*8 + v0*4 + v1*2 + v2;
    atomicMax(&mx_u[cl*256+ch], f2ord(x[nidx*256+ch]));
    if(ch==0) atomicAdd(&cnt8[cl], 1.f);
}

// ---------------- FC + log_softmax ----------------
__global__ __launch_bounds__(256) void k_fc(const unsigned* __restrict__ mx_u,
        const float* __restrict__ cnt8, const float* __restrict__ Wfc,
        const float* __restrict__ bfc, float* __restrict__ out){
    __shared__ float sred[10][256];
    int b = blockIdx.x, tid = threadIdx.x;
    float p[10];
    #pragma unroll
    for(int j=0;j<10;j++) p[j]=0.f;
    for(int idx=tid; idx<2048; idx+=256){
        int v = idx >> 8;
        float val = (cnt8[b*8+v] > 0.f) ? ord2f(mx_u[b*2048+idx]) : 0.f;
        const float* wr = &Wfc[idx*10];
        #pragma unroll
        for(int j=0;j<10;j++) p[j] += val*wr[j];
    }
    #pragma unroll
    for(int j=0;j<10;j++) sred[j][tid]=p[j];
    __syncthreads();
    for(int s=128;s>0;s>>=1){
        if(tid<s){
            #pragma unroll
            for(int j=0;j<10;j++) sred[j][tid]+=sred[j][tid+s];
        }
        __syncthreads();
    }
    if(tid==0){
        float lg[10], mx=-1e30f, se=0.f;
        for(int j=0;j<10;j++){ lg[j]=sred[j][0]+bfc[j]; mx=fmaxf(mx,lg[j]); }
        for(int j=0;j<10;j++) se += expf(lg[j]-mx);
        float lse = mx + logf(se);
        for(int j=0;j<10;j++) out[b*10+j] = lg[j]-lse;
    }
}

extern "C" void kernel_launch(void* const* d_in, const int* in_sizes, int n_in,
                              void* d_out, int out_size, void* d_ws, size_t ws_size,
                              hipStream_t stream){
    const float* x0   = (const float*)d_in[0];
    const float* pos0 = (const float*)d_in[1];
    const float *Wc[5], *rootc[5], *bc[5];
    for(int i=0;i<5;i++){
        Wc[i]    = (const float*)d_in[2+3*i];
        rootc[i] = (const float*)d_in[3+3*i];
        bc[i]    = (const float*)d_in[4+3*i];
    }
    const float *Wa[4], *ba[4];
    for(int i=0;i<4;i++){
        Wa[i] = (const float*)d_in[17+2*i];
        ba[i] = (const float*)d_in[18+2*i];
    }
    const float* Wfc = (const float*)d_in[25];
    const float* bfc = (const float*)d_in[26];
    const int* ei[5]; for(int i=0;i<5;i++) ei[i] = (const int*)d_in[27+i];
    const int* cl[4]; for(int i=0;i<4;i++) cl[i] = (const int*)d_in[32+i];

    const int NPG[5]   = {2048,512,128,32,8};
    const int chans[6] = {1,32,64,96,128,256};
    const float inv2r[5] = {5.f,5.f,4.f,2.f,1.f};
    const int B = 32;
    int Ns[5], Es[5], KdPs[5];
    int totN=0, totWt=0, accTotZ=0, poolTot=0;
    int nodeBase[5], wtBase[5], accOffZ[5], poolOff[4];
    for(int l=0;l<5;l++){
        Ns[l] = B*NPG[l]; Es[l] = Ns[l]*16;
        int Kd = K3*chans[l];
        KdPs[l] = (Kd + 31) & ~31;
        nodeBase[l] = totN; totN += Ns[l];
        wtBase[l] = totWt; totWt += chans[l+1]*KdPs[l];
        if(l >= 1){ accOffZ[l] = accTotZ; accTotZ += Ns[l]*chans[l+1]; }
    }
    for(int l=0;l<4;l++){ poolOff[l] = poolTot; poolTot += Ns[l+1]; }

    size_t off = 0;
    auto alloc = [&](size_t bytes)->void*{
        void* p = (char*)d_ws + off;
        off = (off + bytes + 255) & ~(size_t)255;
        return p;
    };
    // ---- non-zeroed region ----
    float*    x_a    = (float*)   alloc((size_t)65536*32*4);
    float*    x_b    = (float*)   alloc((size_t)16384*32*4);
    float*    pos_a  = (float*)   alloc((size_t)16384*3*4);
    float*    pos_b  = (float*)   alloc((size_t)4096*3*4);
    float*    acc0   = (float*)   alloc((size_t)65536*32*4);   // L1 acc (S==1, no zero)
    int*      slots_a= (int*)     alloc((size_t)totN*64*4);
    int*      cnt_a  = (int*)     alloc((size_t)totN*4);       // fully written by k_pre3
    unsigned short* Wt_a = (unsigned short*)alloc((size_t)totWt*2);
    // ---- zero region (single memset) ----
    size_t zstart = off;
    float*    accz_a = (float*)   alloc((size_t)accTotZ*4);
    unsigned long long* m_p_a = (unsigned long long*)alloc((size_t)poolTot*8);
    float*    cntf_a = (float*)   alloc((size_t)poolTot*4);
    float*    ppos_a = (float*)   alloc((size_t)poolTot*12);
    unsigned* mx_u   = (unsigned*)alloc((size_t)256*256*4);
    float*    cnt8   = (float*)   alloc((size_t)256*4);
    size_t zlen = off - zstart;
    // ---- A tail ----
    unsigned short* A = (unsigned short*)((char*)d_ws + off);
    size_t Abudget = (ws_size > off) ? (ws_size - off) : 0;

    PreArgs pa;
    int wb = 0;
    for(int l=0;l<5;l++){
        pa.src[l] = ei[l];
        pa.dst[l] = ei[l] + Es[l];
        pa.cnt[l] = cnt_a + nodeBase[l];
        pa.slots[l] = slots_a + (size_t)nodeBase[l]*64;
        pa.npg[l] = NPG[l];
        pa.W[l] = Wc[l]; pa.Wt[l] = Wt_a + wtBase[l];
        pa.Kd[l] = K3*chans[l]; pa.KdP[l] = KdPs[l]; pa.Co[l] = chans[l+1];
        pa.fillFirst[l] = l*B;
        pa.ktiles[l] = (KdPs[l] + 63)/64;
        pa.wtFirst[l] = wb; wb += pa.ktiles[l] * ((chans[l+1] + 63)/64);
    }
    pa.fillFirst[5] = 5*B;
    pa.wtFirst[5] = wb;
    int preBlocks = 5*B + wb;

    hipMemsetAsync((char*)d_ws + zstart, 0, zlen, stream);
    k_pre3<<<preBlocks, 1024, 0, stream>>>(pa);

    const float* xin = x0;
    const float* pin = pos0;

    for(int L=0; L<5; L++){
        int N  = Ns[L];
        int Cin = chans[L], Co = chans[L+1];
        int KdP = KdPs[L];
        const int* cntL   = cnt_a + nodeBase[L];
        const int* slotsL = slots_a + (size_t)nodeBase[L]*64;
        const unsigned short* WtL = pa.Wt[L];
        float* accL = (L == 0) ? acc0 : (accz_a + accOffZ[L]);

        size_t nodeb = (size_t)KdP*2;
        int Mc = (int)(Abudget / nodeb);
        Mc = (Mc / 128) * 128;
        if(Mc < 128) Mc = 128;
        if(Mc > N) Mc = N;

        for(int rn0=0; rn0<N; rn0+=Mc){
            int rn1 = (rn0+Mc < N) ? rn0+Mc : N;
            int Mr  = rn1 - rn0;
            if(Cin==1)
                k_build1<<<Mr/32, 256, 0, stream>>>(slotsL, cntL, pin, xin, inv2r[L], rn0, KdP, A);
            else
                k_build2<<<dim3(Mr, Cin/32), 256, 0, stream>>>(slotsL, cntL, pin, xin,
                                                               inv2r[L], rn0, Cin, KdP, A);

            int BN = (Co % 64 == 0) ? 64 : 32;
            int gx = Mr/128, gy = Co/BN;
            int S = 768/(gx*gy);
            if(S < 1) S = 1;
            if(L == 0) S = 1;   // acc0 is not pre-zeroed; must use plain stores
            int maxS = KdP/32;
            if(S > maxS) S = maxS;
            int Kper = ((KdP + S - 1)/S + 31) & ~31;
            S = (KdP + Kper - 1)/Kper;
            dim3 g(gx, gy, S);
            if(BN == 64) k_mfma<64><<<g, 256, 0, stream>>>(A, WtL, accL, rn0, Co, KdP, Kper);
            else         k_mfma<32><<<g, 256, 0, stream>>>(A, WtL, accL, rn0, Co, KdP, Kper);
        }

        float* y = x_a;
        int NPB = 256/Co; if(NPB < 1) NPB = 1;
        int thr = NPB*Co;
        size_t smb = (size_t)(NPB*Cin + NPB*Co)*4;
        bool haspool = (L < 4);
        k_finish2<<<(N+NPB-1)/NPB, thr, smb, stream>>>(accL, cntL, xin, rootc[L], bc[L],
            haspool?Wa[L]:nullptr, haspool?ba[L]:nullptr, y,
            haspool?cl[L]:nullptr, pin,
            haspool?(m_p_a+poolOff[L]):nullptr,
            haspool?(cntf_a+poolOff[L]):nullptr,
            haspool?(ppos_a+(size_t)poolOff[L]*3):nullptr,
            N, Cin, Co, NPB);

        if(haspool){
            int nc = Ns[L+1];
            float* pout = (L%2==0) ? pos_a : pos_b;
            k_pool3<<<(nc*Co+255)/256, 256, 0, stream>>>(m_p_a+poolOff[L], cntf_a+poolOff[L],
                ppos_a+(size_t)poolOff[L]*3, y, x_b, pout, nc, Co, N);
            xin = x_b; pin = pout;
        }
    }

    k_vox<<<256, 256, 0, stream>>>(x_a, pin, mx_u, cnt8);
    k_fc<<<32, 256, 0, stream>>>(mx_u, cnt8, Wfc, bfc, (float*)d_out);
}

// Round 16
// 438.945 us; speedup vs baseline: 1.0857x; 1.0280x over previous
//
#include <hip/hip_runtime.h>
#include <hip/hip_bf16.h>
#include <cstdint>
#include <cstddef>

#define KS 5
#define K3 125

typedef __attribute__((ext_vector_type(8))) short bf16x8;
typedef __attribute__((ext_vector_type(4))) float f32x4;

struct PreArgs {
    const int* src[5]; const int* dst[5];
    int* cnt[5]; int* slots[5];
    int npg[5]; int subs[5];
    const float* W[5]; unsigned short* Wt[5];
    int Kd[5], KdP[5], Co[5];
    int fillFirst[6]; int wtFirst[6]; int ktiles[5];
};

__device__ __forceinline__ unsigned f2ord(float f){
    unsigned u = __float_as_uint(f);
    return (u & 0x80000000u) ? ~u : (u | 0x80000000u);
}
__device__ __forceinline__ float ord2f(unsigned u){
    unsigned b = (u & 0x80000000u) ? (u & 0x7FFFFFFFu) : ~u;
    return __uint_as_float(b);
}
__device__ __forceinline__ unsigned short f2bf(float f){
    unsigned u = __float_as_uint(f);
    u = (u + 0x7FFFu + ((u >> 16) & 1u)) >> 16;
    return (unsigned short)u;
}
__device__ __forceinline__ unsigned pk_bf16(float a, float b){
    __hip_bfloat162 p = __float22bfloat162_rn(make_float2(a, b));
    return *(unsigned*)&p;
}

// ---------------- fused preamble: LDS-staged slot fill + W transpose ----------------
// fill blocks: one per (layer, graph, node-range<=256). Slot tile built in LDS,
// written out as full coalesced lines. Zero global atomics, zero random stores.
__global__ __launch_bounds__(1024) void k_pre4(PreArgs a){
    __shared__ int sbuf[256*64 + 256];   // 65 KB; wt phase reuses as float t[64][65]
    int b = blockIdx.x;
    int tid = threadIdx.x;
    if(b < a.fillFirst[5]){
        int l = 0;
        while(b >= a.fillFirst[l+1]) l++;
        int j = b - a.fillFirst[l];
        int subs = a.subs[l];
        int g = j / subs;
        int r = j - g*subs;
        int npg = a.npg[l];
        int NPR = npg / subs;            // <=256 by construction
        int E1 = npg*16;
        int nbase = g*npg + r*NPR;
        int* scnt  = sbuf;               // NPR counters
        int* sslot = sbuf + 256;         // NPR*64 slot tile
        for(int i=tid; i<NPR; i+=1024) scnt[i] = 0;
        __syncthreads();
        const int* srcp = a.src[l] + (size_t)g*E1;
        const int* dstp = a.dst[l] + (size_t)g*E1;
        int gn0 = g*npg;
        for(int e=tid; e<E1; e+=1024){
            int d = dstp[e] - nbase;
            if((unsigned)d < (unsigned)NPR){
                int s = srcp[e];
                int p = __hip_atomic_fetch_add(&scnt[d], 1,
                            __ATOMIC_RELAXED, __HIP_MEMORY_SCOPE_WORKGROUP);
                if(p < 64) sslot[d*64 + p] = s;
            }
        }
        __syncthreads();
        int* gs = a.slots[l] + (size_t)nbase*64;
        int tot = NPR*64;
        for(int i=tid*4; i<tot; i+=4096)
            *(int4*)&gs[i] = *(int4*)&sslot[i];
        int* cg = a.cnt[l] + nbase;
        for(int i=tid; i<NPR; i+=1024) cg[i] = scnt[i];
        (void)gn0;
        return;
    }
    int r = b - a.fillFirst[5];
    int l = 0;
    while(r >= a.wtFirst[l+1]) l++;
    int idx = r - a.wtFirst[l];
    int kb = (idx % a.ktiles[l])*64;
    int cb = (idx / a.ktiles[l])*64;
    int Kd = a.Kd[l], KdP = a.KdP[l], Co = a.Co[l];
    const float* W = a.W[l];
    unsigned short* Wt = a.Wt[l];
    float (*t)[65] = (float(*)[65])sbuf;
    int cc = tid & 63, rg = tid >> 6;           // rg in [0,16)
    #pragma unroll
    for(int i=0;i<4;i++){
        int kl = rg + i*16;
        int kk = kb + kl, co = cb + cc;
        t[kl][cc] = (kk < Kd && co < Co) ? W[(size_t)kk*Co + co] : 0.f;
    }
    __syncthreads();
    int kl = tid & 63;
    #pragma unroll
    for(int i=0;i<4;i++){
        int col = rg + i*16;
        int co = cb + col;
        int kk = kb + kl;
        if(co < Co && kk < KdP) Wt[(size_t)co*KdP + kk] = f2bf(t[kl][col]);
    }
}

// ---------------- spline basis helper ----------------
__device__ __forceinline__ void spline_meta(float dx, float dy, float dz, float inv2r,
        float* wgt, int* ki){
    float fr[3]; int k0[3];
    float dd[3] = {dx, dy, dz};
    #pragma unroll
    for(int dim=0; dim<3; dim++){
        float p = dd[dim]*inv2r + 0.5f;
        p = fminf(fmaxf(p, 0.f), 1.f);
        float u = p*4.0f;
        float kf = fminf(floorf(u), 3.f);
        fr[dim] = u - kf; k0[dim] = (int)kf;
    }
    #pragma unroll
    for(int bits=0; bits<8; bits++){
        wgt[bits] = ((bits&1)? fr[0] : 1.f-fr[0])
                  * ((bits&2)? fr[1] : 1.f-fr[1])
                  * ((bits&4)? fr[2] : 1.f-fr[2]);
        ki[bits]  = (k0[0]+(bits&1)) + KS*(k0[1]+((bits>>1)&1)) + KS*KS*(k0[2]+((bits>>2)&1));
    }
}

// ---------------- build A, 32-ci-slice per block, 16-group float2 drain ----------------
__global__ __launch_bounds__(256) void k_build2(const int* __restrict__ slots,
        const int* __restrict__ cnt, const float* __restrict__ pos,
        const float* __restrict__ x,
        float inv2r, int n0, int Cin, int KdP, unsigned short* __restrict__ A){
    const int CH = 32;
    __shared__ float row[K3*32];
    __shared__ float xbuf[CH*32];
    __shared__ float ew[CH][8];
    __shared__ unsigned short bkt[16][CH];
    __shared__ int bcnt[16];
    __shared__ int esrc[CH];
    int tid = threadIdx.x;
    int node = n0 + blockIdx.x;
    int ci0 = blockIdx.y*32;
    for(int i=tid; i<K3*32; i+=256) row[i] = 0.f;
    int ecnt = min(cnt[node], 64);
    const int* sl = slots + (size_t)node*64;
    float pdx = pos[node*3+0], pdy = pos[node*3+1], pdz = pos[node*3+2];

    for(int c0=0; c0<ecnt; c0+=CH){
        int cc2 = min(CH, ecnt-c0);
        __syncthreads();
        if(tid < 16) bcnt[tid] = 0;
        float w[8]; int ki[8];
        if(tid < cc2){
            int s = sl[c0+tid];
            esrc[tid] = s;
            spline_meta(pdx-pos[s*3+0], pdy-pos[s*3+1], pdz-pos[s*3+2], inv2r, w, ki);
            #pragma unroll
            for(int b=0;b<8;b++) ew[tid][b] = w[b];
        }
        __syncthreads();
        if(tid < cc2){
            #pragma unroll
            for(int b=0;b<8;b++){
                int g = ki[b] & 15;
                int p = atomicAdd(&bcnt[g], 1);
                bkt[g][p] = (unsigned short)((ki[b]<<8) | (tid<<3) | b);
            }
        }
        for(int i=tid; i<cc2*32; i+=256){
            int e = i >> 5, ci = i & 31;
            xbuf[i] = x[(size_t)esrc[e]*Cin + ci0 + ci];
        }
        __syncthreads();
        int g  = tid >> 4;
        int cl = (tid & 15)*2;
        int ng = bcnt[g];
        for(int i=0; i<ng; i++){
            unsigned v = bkt[g][i];
            int kq = v >> 8;
            int e  = (v >> 3) & 31;
            float wv = ew[e][v & 7];
            float2 xv = *(float2*)&xbuf[e*32 + cl];
            float2* rp = (float2*)&row[kq*32 + cl];
            float2 rv = *rp;
            rv.x += wv*xv.x;
            rv.y += wv*xv.y;
            *rp = rv;
        }
    }
    __syncthreads();
    size_t gbase = (size_t)blockIdx.x*KdP + ci0;
    for(int i=tid*4; i<K3*32; i+=1024){
        int k = i >> 5, c = i & 31;
        uint2 pk;
        pk.x = pk_bf16(row[i],   row[i+1]);
        pk.y = pk_bf16(row[i+2], row[i+3]);
        *(uint2*)&A[gbase + (size_t)k*Cin + c] = pk;
    }
}

// ---------------- build for Cin==1 (layer 1) ----------------
__global__ __launch_bounds__(256) void k_build1(const int* __restrict__ slots,
        const int* __restrict__ cnt, const float* __restrict__ pos,
        const float* __restrict__ x,
        float inv2r, int n0, int KdP, unsigned short* __restrict__ A){
    const int NB = 32, KD = K3;
    __shared__ float rows[NB*KD];
    int tid = threadIdx.x;
    for(int i=tid; i<NB*KD; i+=256) rows[i] = 0.f;
    __syncthreads();
    int nb = tid >> 3;
    int grp = tid & 7;
    int node = n0 + blockIdx.x*NB + nb;
    float* row = rows + nb*KD;
    float pdx = pos[node*3+0], pdy = pos[node*3+1], pdz = pos[node*3+2];
    int ecnt = min(cnt[node], 64);
    const int* sl = slots + (size_t)node*64;
    for(int ii=grp; ii<ecnt; ii+=8){
        int s = sl[ii];
        float w[8]; int ki[8];
        spline_meta(pdx-pos[s*3+0], pdy-pos[s*3+1], pdz-pos[s*3+2], inv2r, w, ki);
        float xs = x[s];
        #pragma unroll
        for(int b=0; b<8; b++)
            __hip_atomic_fetch_add(&row[ki[b]], w[b]*xs, __ATOMIC_RELAXED, __HIP_MEMORY_SCOPE_WORKGROUP);
    }
    __syncthreads();
    size_t gbase = (size_t)blockIdx.x*NB*KdP;
    int tot = NB*KdP;
    for(int i=tid*2; i<tot; i+=512){
        int nbw = i / KdP;
        int kk  = i - nbw*KdP;
        float v0 = (kk   < KD) ? rows[nbw*KD + kk]   : 0.f;
        float v1 = (kk+1 < KD) ? rows[nbw*KD + kk+1] : 0.f;
        *(unsigned*)&A[gbase + i] = pk_bf16(v0, v1);
    }
}

// ---------------- MFMA GEMM (BN in {32,64}) ----------------
template<int BN>
__global__ __launch_bounds__(256) void k_mfma(const unsigned short* __restrict__ A,
        const unsigned short* __restrict__ Wt, float* __restrict__ acc,
        int n0, int Co, int KdP, int Kper){
    const int NBF = BN/16;
    __shared__ unsigned short Al[128*32];
    __shared__ unsigned short Bl[BN*32];
    int tid = threadIdx.x;
    int m0 = blockIdx.x*128, nb0 = blockIdx.y*BN;
    int kstart = blockIdx.z*Kper;
    int kend = min(KdP, kstart + Kper);
    if(kstart >= kend) return;
    int w = tid >> 6, l = tid & 63, lm = l & 15, lk = l >> 4;
    f32x4 c[2][NBF];
    #pragma unroll
    for(int i=0;i<2;i++)
        #pragma unroll
        for(int j=0;j<NBF;j++) c[i][j] = (f32x4){0,0,0,0};
    int ar = tid >> 1, ah = (tid & 1)*16;

    for(int k0=kstart; k0<kend; k0+=32){
        const unsigned short* ga = A + (size_t)(m0+ar)*KdP + k0 + ah;
        *(uint4*)&Al[ar*32 + ah]     = *(const uint4*)ga;
        *(uint4*)&Al[ar*32 + ah + 8] = *(const uint4*)(ga + 8);
        if(tid < BN*4){
            int bn = tid >> 2, bk = (tid & 3)*8;
            *(uint4*)&Bl[bn*32 + bk] = *(const uint4*)(Wt + (size_t)(nb0+bn)*KdP + k0 + bk);
        }
        __syncthreads();
        bf16x8 af[2], bfr[NBF];
        #pragma unroll
        for(int i=0;i<2;i++) af[i] = *(bf16x8*)&Al[(w*32 + i*16 + lm)*32 + lk*8];
        #pragma unroll
        for(int j=0;j<NBF;j++) bfr[j] = *(bf16x8*)&Bl[(j*16 + lm)*32 + lk*8];
        #pragma unroll
        for(int i=0;i<2;i++)
            #pragma unroll
            for(int j=0;j<NBF;j++)
                c[i][j] = __builtin_amdgcn_mfma_f32_16x16x32_bf16(af[i], bfr[j], c[i][j], 0,0,0);
        __syncthreads();
    }
    #pragma unroll
    for(int i=0;i<2;i++){
        int mb = n0 + m0 + w*32 + i*16 + lk*4;
        #pragma unroll
        for(int j=0;j<NBF;j++){
            int col = nb0 + j*16 + lm;
            if(gridDim.z == 1){
                #pragma unroll
                for(int r=0;r<4;r++) acc[(size_t)(mb+r)*Co + col] = c[i][j][r];
            } else {
                #pragma unroll
                for(int r=0;r<4;r++) atomicAdd(&acc[(size_t)(mb+r)*Co + col], c[i][j][r]);
            }
        }
    }
}

// ---------------- conv epilogue + fused attention-pool atomics ----------------
__global__ void k_finish2(const float* __restrict__ acc, const int* __restrict__ deg,
        const float* __restrict__ xin, const float* __restrict__ root,
        const float* __restrict__ bias, const float* __restrict__ Wa,
        const float* __restrict__ ba, float* __restrict__ y,
        const int* __restrict__ cl, const float* __restrict__ pin,
        unsigned long long* __restrict__ m_p, float* __restrict__ cntf,
        float* __restrict__ ppos, int N, int Cin, int Co, int NPB){
    extern __shared__ float sm[];
    float* xs  = sm;
    float* red = sm + NPB*Cin;
    int tid = threadIdx.x;
    int nl = tid / Co, co = tid - nl*Co;
    int n = blockIdx.x*NPB + nl;
    bool act = (n < N);
    if(act) for(int c=co; c<Cin; c+=Co) xs[nl*Cin + c] = xin[(size_t)n*Cin + c];
    __syncthreads();
    float yv = 0.f;
    if(act){
        float v = acc[(size_t)n*Co + co] / (float)max(deg[n], 1);
        float rt = 0.f;
        for(int c=0; c<Cin; c++) rt += xs[nl*Cin + c]*root[(size_t)c*Co + co];
        v += rt + bias[co];
        yv = v > 0.f ? v : expm1f(v);
        y[(size_t)n*Co + co] = yv;
    }
    if(m_p){
        float av = act ? yv * Wa[co*2] : 0.f;
        if(Co <= 64){
            #pragma unroll
            for(int off=32; off>0; off>>=1)
                if(off < Co) av += __shfl_xor(av, off, 64);
        } else {
            red[tid] = av;
            __syncthreads();
            int cur = Co;
            while(cur > 1){
                int half = (cur+1) >> 1;
                if(co < cur-half) red[nl*Co+co] += red[nl*Co+co+half];
                __syncthreads();
                cur = half;
            }
            av = red[nl*Co];
        }
        if(act && co==0){
            float attv = av + ba[0];
            int c = cl[n];
            unsigned long long pk = ((unsigned long long)f2ord(attv) << 32) | (unsigned)(~n);
            atomicMax(&m_p[c], pk);
            atomicAdd(&cntf[c], 1.f);
            atomicAdd(&ppos[c*3+0], pin[n*3+0]);
            atomicAdd(&ppos[c*3+1], pin[n*3+1]);
            atomicAdd(&ppos[c*3+2], pin[n*3+2]);
        }
    }
}

// ---------------- pool gather ----------------
__global__ void k_pool3(const unsigned long long* __restrict__ m_p, const float* __restrict__ cntf,
        const float* __restrict__ ppos, const float* __restrict__ x,
        float* __restrict__ xo, float* __restrict__ poso, int nc, int Co, int nmax){
    int t = blockIdx.x*blockDim.x + threadIdx.x;
    if(t >= nc*Co) return;
    int c = t / Co;
    int co = t - c*Co;
    unsigned s = ~(unsigned)(m_p[c] & 0xFFFFFFFFull);
    s = min(s, (unsigned)(nmax-1));
    xo[(size_t)c*Co + co] = x[(size_t)s*Co + co];
    if(co < 3) poso[c*3+co] = ppos[c*3+co] / fmaxf(cntf[c], 1.f);
}

// ---------------- final voxel max pool ----------------
__global__ void k_vox(const float* __restrict__ x, const float* __restrict__ pos,
        unsigned* __restrict__ mx_u, float* __restrict__ cnt8){
    int nidx = blockIdx.x, ch = threadIdx.x;
    int v0 = min(max((int)floorf(pos[nidx*3+0]+0.5f),0),1);
    int v1 = min(max((int)floorf(pos[nidx*3+1]+0.5f),0),1);
    int v2 = min(max((int)floorf(pos[nidx*3+2]+0.5f),0),1);
    int b = nidx >> 3;
    int cl = b*8 + v0*4 + v1*2 + v2;
    atomicMax(&mx_u[cl*256+ch], f2ord(x[nidx*256+ch]));
    if(ch==0) atomicAdd(&cnt8[cl], 1.f);
}

// ---------------- FC + log_softmax ----------------
__global__ __launch_bounds__(256) void k_fc(const unsigned* __restrict__ mx_u,
        const float* __restrict__ cnt8, const float* __restrict__ Wfc,
        const float* __restrict__ bfc, float* __restrict__ out){
    __shared__ float sred[10][256];
    int b = blockIdx.x, tid = threadIdx.x;
    float p[10];
    #pragma unroll
    for(int j=0;j<10;j++) p[j]=0.f;
    for(int idx=tid; idx<2048; idx+=256){
        int v = idx >> 8;
        float val = (cnt8[b*8+v] > 0.f) ? ord2f(mx_u[b*2048+idx]) : 0.f;
        const float* wr = &Wfc[idx*10];
        #pragma unroll
        for(int j=0;j<10;j++) p[j] += val*wr[j];
    }
    #pragma unroll
    for(int j=0;j<10;j++) sred[j][tid]=p[j];
    __syncthreads();
    for(int s=128;s>0;s>>=1){
        if(tid<s){
            #pragma unroll
            for(int j=0;j<10;j++) sred[j][tid]+=sred[j][tid+s];
        }
        __syncthreads();
    }
    if(tid==0){
        float lg[10], mx=-1e30f, se=0.f;
        for(int j=0;j<10;j++){ lg[j]=sred[j][0]+bfc[j]; mx=fmaxf(mx,lg[j]); }
        for(int j=0;j<10;j++) se += expf(lg[j]-mx);
        float lse = mx + logf(se);
        for(int j=0;j<10;j++) out[b*10+j] = lg[j]-lse;
    }
}

extern "C" void kernel_launch(void* const* d_in, const int* in_sizes, int n_in,
                              void* d_out, int out_size, void* d_ws, size_t ws_size,
                              hipStream_t stream){
    const float* x0   = (const float*)d_in[0];
    const float* pos0 = (const float*)d_in[1];
    const float *Wc[5], *rootc[5], *bc[5];
    for(int i=0;i<5;i++){
        Wc[i]    = (const float*)d_in[2+3*i];
        rootc[i] = (const float*)d_in[3+3*i];
        bc[i]    = (const float*)d_in[4+3*i];
    }
    const float *Wa[4], *ba[4];
    for(int i=0;i<4;i++){
        Wa[i] = (const float*)d_in[17+2*i];
        ba[i] = (const float*)d_in[18+2*i];
    }
    const float* Wfc = (const float*)d_in[25];
    const float* bfc = (const float*)d_in[26];
    const int* ei[5]; for(int i=0;i<5;i++) ei[i] = (const int*)d_in[27+i];
    const int* cl[4]; for(int i=0;i<4;i++) cl[i] = (const int*)d_in[32+i];

    const int NPG[5]   = {2048,512,128,32,8};
    const int chans[6] = {1,32,64,96,128,256};
    const float inv2r[5] = {5.f,5.f,4.f,2.f,1.f};
    const int B = 32;
    const int SUBS[5] = {8,2,1,1,1};
    int Ns[5], Es[5], KdPs[5];
    int totN=0, totWt=0, accTotZ=0, poolTot=0;
    int nodeBase[5], wtBase[5], accOffZ[5], poolOff[4];
    for(int l=0;l<5;l++){
        Ns[l] = B*NPG[l]; Es[l] = Ns[l]*16;
        int Kd = K3*chans[l];
        KdPs[l] = (Kd + 31) & ~31;
        nodeBase[l] = totN; totN += Ns[l];
        wtBase[l] = totWt; totWt += chans[l+1]*KdPs[l];
        if(l >= 1){ accOffZ[l] = accTotZ; accTotZ += Ns[l]*chans[l+1]; }
    }
    for(int l=0;l<4;l++){ poolOff[l] = poolTot; poolTot += Ns[l+1]; }

    size_t off = 0;
    auto alloc = [&](size_t bytes)->void*{
        void* p = (char*)d_ws + off;
        off = (off + bytes + 255) & ~(size_t)255;
        return p;
    };
    // ---- non-zeroed region ----
    float*    x_a    = (float*)   alloc((size_t)65536*32*4);
    float*    x_b    = (float*)   alloc((size_t)16384*32*4);
    float*    pos_a  = (float*)   alloc((size_t)16384*3*4);
    float*    pos_b  = (float*)   alloc((size_t)4096*3*4);
    float*    acc0   = (float*)   alloc((size_t)65536*32*4);   // L1 acc (S==1, no zero)
    int*      slots_a= (int*)     alloc((size_t)totN*64*4);
    int*      cnt_a  = (int*)     alloc((size_t)totN*4);       // fully written by k_pre4
    unsigned short* Wt_a = (unsigned short*)alloc((size_t)totWt*2);
    // ---- zero region (single memset) ----
    size_t zstart = off;
    float*    accz_a = (float*)   alloc((size_t)accTotZ*4);
    unsigned long long* m_p_a = (unsigned long long*)alloc((size_t)poolTot*8);
    float*    cntf_a = (float*)   alloc((size_t)poolTot*4);
    float*    ppos_a = (float*)   alloc((size_t)poolTot*12);
    unsigned* mx_u   = (unsigned*)alloc((size_t)256*256*4);
    float*    cnt8   = (float*)   alloc((size_t)256*4);
    size_t zlen = off - zstart;
    // ---- A tail ----
    unsigned short* A = (unsigned short*)((char*)d_ws + off);
    size_t Abudget = (ws_size > off) ? (ws_size - off) : 0;

    PreArgs pa;
    int fb = 0, wb = 0;
    for(int l=0;l<5;l++){
        pa.src[l] = ei[l];
        pa.dst[l] = ei[l] + Es[l];
        pa.cnt[l] = cnt_a + nodeBase[l];
        pa.slots[l] = slots_a + (size_t)nodeBase[l]*64;
        pa.npg[l] = NPG[l];
        pa.subs[l] = SUBS[l];
        pa.W[l] = Wc[l]; pa.Wt[l] = Wt_a + wtBase[l];
        pa.Kd[l] = K3*chans[l]; pa.KdP[l] = KdPs[l]; pa.Co[l] = chans[l+1];
        pa.fillFirst[l] = fb; fb += B*SUBS[l];
        pa.ktiles[l] = (KdPs[l] + 63)/64;
        pa.wtFirst[l] = wb; wb += pa.ktiles[l] * ((chans[l+1] + 63)/64);
    }
    pa.fillFirst[5] = fb;
    pa.wtFirst[5] = wb;
    int preBlocks = fb + wb;

    hipMemsetAsync((char*)d_ws + zstart, 0, zlen, stream);
    k_pre4<<<preBlocks, 1024, 0, stream>>>(pa);

    const float* xin = x0;
    const float* pin = pos0;

    for(int L=0; L<5; L++){
        int N  = Ns[L];
        int Cin = chans[L], Co = chans[L+1];
        int KdP = KdPs[L];
        const int* cntL   = cnt_a + nodeBase[L];
        const int* slotsL = slots_a + (size_t)nodeBase[L]*64;
        const unsigned short* WtL = pa.Wt[L];
        float* accL = (L == 0) ? acc0 : (accz_a + accOffZ[L]);

        size_t nodeb = (size_t)KdP*2;
        int Mc = (int)(Abudget / nodeb);
        Mc = (Mc / 128) * 128;
        if(Mc < 128) Mc = 128;
        if(Mc > N) Mc = N;

        for(int rn0=0; rn0<N; rn0+=Mc){
            int rn1 = (rn0+Mc < N) ? rn0+Mc : N;
            int Mr  = rn1 - rn0;
            if(Cin==1)
                k_build1<<<Mr/32, 256, 0, stream>>>(slotsL, cntL, pin, xin, inv2r[L], rn0, KdP, A);
            else
                k_build2<<<dim3(Mr, Cin/32), 256, 0, stream>>>(slotsL, cntL, pin, xin,
                                                               inv2r[L], rn0, Cin, KdP, A);

            int BN = (Co % 64 == 0) ? 64 : 32;
            int gx = Mr/128, gy = Co/BN;
            int S = 768/(gx*gy);
            if(S < 1) S = 1;
            if(L == 0) S = 1;   // acc0 is not pre-zeroed; must use plain stores
            int maxS = KdP/32;
            if(S > maxS) S = maxS;
            int Kper = ((KdP + S - 1)/S + 31) & ~31;
            S = (KdP + Kper - 1)/Kper;
            dim3 g(gx, gy, S);
            if(BN == 64) k_mfma<64><<<g, 256, 0, stream>>>(A, WtL, accL, rn0, Co, KdP, Kper);
            else         k_mfma<32><<<g, 256, 0, stream>>>(A, WtL, accL, rn0, Co, KdP, Kper);
        }

        float* y = x_a;
        int NPB = 256/Co; if(NPB < 1) NPB = 1;
        int thr = NPB*Co;
        size_t smb = (size_t)(NPB*Cin + NPB*Co)*4;
        bool haspool = (L < 4);
        k_finish2<<<(N+NPB-1)/NPB, thr, smb, stream>>>(accL, cntL, xin, rootc[L], bc[L],
            haspool?Wa[L]:nullptr, haspool?ba[L]:nullptr, y,
            haspool?cl[L]:nullptr, pin,
            haspool?(m_p_a+poolOff[L]):nullptr,
            haspool?(cntf_a+poolOff[L]):nullptr,
            haspool?(ppos_a+(size_t)poolOff[L]*3):nullptr,
            N, Cin, Co, NPB);

        if(haspool){
            int nc = Ns[L+1];
            float* pout = (L%2==0) ? pos_a : pos_b;
            k_pool3<<<(nc*Co+255)/256, 256, 0, stream>>>(m_p_a+poolOff[L], cntf_a+poolOff[L],
                ppos_a+(size_t)poolOff[L]*3, y, x_b, pout, nc, Co, N);
            xin = x_b; pin = pout;
        }
    }

    k_vox<<<256, 256, 0, stream>>>(x_a, pin, mx_u, cnt8);
    k_fc<<<32, 256, 0, stream>>>(mx_u, cnt8, Wfc, bfc, (float*)d_out);
}